// Round 1
// baseline (651.759 us; speedup 1.0000x reference)
//
#include <hip/hip_runtime.h>
#include <math.h>

// Problem constants (fixed by setup_inputs)
#define BD   1024            // batch B
#define LW   80              // walk length L
#define AA   76              // anchors A = L - w + 1, w = 5
#define NEGS 4               // negatives per anchor
#define D    128             // embed dim
#define PAIRS (BD * AA)      // 77824 (b,a) pairs
#define PAIRS_PER_WAVE 8
#define WAVES_PER_BLOCK 4
#define NBLOCKS (PAIRS / (PAIRS_PER_WAVE * WAVES_PER_BLOCK))  // 2432, exact

// Numerically-stable softplus matching jax.nn.softplus
__device__ __forceinline__ float softplus(float x) {
    return fmaxf(x, 0.0f) + log1pf(__expf(-fabsf(x)));
}

__global__ __launch_bounds__(256) void sg_partial(
    const int* __restrict__ walk, const int* __restrict__ neg,
    const float* __restrict__ embed, float* __restrict__ ws)
{
    __shared__ float s_wsum[WAVES_PER_BLOCK];
    const int tid  = threadIdx.x;
    const int wave = tid >> 6;
    const int lane = tid & 63;
    const int gwave = blockIdx.x * WAVES_PER_BLOCK + wave;
    const int pbase = gwave * PAIRS_PER_WAVE;   // 8 consecutive pairs -> L1/L2 row reuse

    float wsum = 0.0f;

    #pragma unroll 1
    for (int i = 0; i < PAIRS_PER_WAVE; ++i) {
        const int p = pbase + i;                 // < 77824 always (exact tiling)
        const int b = p / AA;
        const int a = p - b * AA;

        // index loads (wave-uniform addresses, L1-broadcast)
        const int* wrow = walk + b * LW + a;
        const int anc = wrow[0];
        const int t0 = wrow[1];
        const int t1 = wrow[2];
        const int t2 = wrow[3];
        const int t3 = wrow[4];
        const int4 nv = *(const int4*)(neg + (size_t)(b * AA + a) * NEGS); // 16B aligned

        // anchor fragment: lane i holds embed[anc][2i .. 2i+1]
        const size_t loff = (size_t)(lane * 2);
        const float2 ea = *(const float2*)(embed + (size_t)anc * D + loff);

        // issue all 8 target loads first (MLP), then FMA
        const float2 e0 = *(const float2*)(embed + (size_t)t0   * D + loff);
        const float2 e1 = *(const float2*)(embed + (size_t)t1   * D + loff);
        const float2 e2 = *(const float2*)(embed + (size_t)t2   * D + loff);
        const float2 e3 = *(const float2*)(embed + (size_t)t3   * D + loff);
        const float2 e4 = *(const float2*)(embed + (size_t)nv.x * D + loff);
        const float2 e5 = *(const float2*)(embed + (size_t)nv.y * D + loff);
        const float2 e6 = *(const float2*)(embed + (size_t)nv.z * D + loff);
        const float2 e7 = *(const float2*)(embed + (size_t)nv.w * D + loff);

        float a0 = fmaf(ea.x, e0.x, ea.y * e0.y);
        float a1 = fmaf(ea.x, e1.x, ea.y * e1.y);
        float a2 = fmaf(ea.x, e2.x, ea.y * e2.y);
        float a3 = fmaf(ea.x, e3.x, ea.y * e3.y);
        float a4 = fmaf(ea.x, e4.x, ea.y * e4.y);
        float a5 = fmaf(ea.x, e5.x, ea.y * e5.y);
        float a6 = fmaf(ea.x, e6.x, ea.y * e6.y);
        float a7 = fmaf(ea.x, e7.x, ea.y * e7.y);

        // 64-lane butterfly reduction of 8 logits
        #pragma unroll
        for (int m = 1; m < 64; m <<= 1) {
            a0 += __shfl_xor(a0, m, 64);
            a1 += __shfl_xor(a1, m, 64);
            a2 += __shfl_xor(a2, m, 64);
            a3 += __shfl_xor(a3, m, 64);
            a4 += __shfl_xor(a4, m, 64);
            a5 += __shfl_xor(a5, m, 64);
            a6 += __shfl_xor(a6, m, 64);
            a7 += __shfl_xor(a7, m, 64);
        }

        // all lanes hold identical full sums; compute redundantly (SIMD-free)
        wsum += softplus(-a0) + softplus(-a1) + softplus(-a2) + softplus(-a3)
              + softplus( a4) + softplus( a5) + softplus( a6) + softplus( a7);
    }

    if (lane == 0) s_wsum[wave] = wsum;
    __syncthreads();
    if (tid == 0)
        ws[blockIdx.x] = s_wsum[0] + s_wsum[1] + s_wsum[2] + s_wsum[3];
}

__global__ __launch_bounds__(256) void sg_reduce(
    const float* __restrict__ ws, float* __restrict__ out)
{
    __shared__ float s[WAVES_PER_BLOCK];
    const int tid = threadIdx.x;
    float sum = 0.0f;
    for (int i = tid; i < NBLOCKS; i += 256) sum += ws[i];
    #pragma unroll
    for (int m = 1; m < 64; m <<= 1) sum += __shfl_xor(sum, m, 64);
    const int wave = tid >> 6;
    const int lane = tid & 63;
    if (lane == 0) s[wave] = sum;
    __syncthreads();
    if (tid == 0) {
        const float total = (float)((size_t)PAIRS * 8);   // 622592 logits
        out[0] = (s[0] + s[1] + s[2] + s[3]) * (1.0f / total);
    }
}

extern "C" void kernel_launch(void* const* d_in, const int* in_sizes, int n_in,
                              void* d_out, int out_size, void* d_ws, size_t ws_size,
                              hipStream_t stream) {
    const int*   walk  = (const int*)d_in[0];
    const int*   neg   = (const int*)d_in[1];
    const float* embed = (const float*)d_in[2];
    float* ws  = (float*)d_ws;   // NBLOCKS floats of scratch (~9.5 KB)
    float* out = (float*)d_out;

    sg_partial<<<NBLOCKS, 256, 0, stream>>>(walk, neg, embed, ws);
    sg_reduce<<<1, 256, 0, stream>>>(ws, out);
}

// Round 2
// 587.700 us; speedup vs baseline: 1.1090x; 1.1090x over previous
//
#include <hip/hip_runtime.h>
#include <math.h>

// Problem constants (fixed by setup_inputs)
#define BD   1024            // batch B
#define LW   80              // walk length L
#define AA   76              // anchors A = L - w + 1, w = 5
#define NEGS 4               // negatives per anchor
#define D    128             // embed dim
#define PAIRS (BD * AA)      // 77824 (b,a) pairs
#define WAVES_PER_BLOCK 4
#define PAIRS_PER_WAVE 19    // 76 = 4 waves x 19 anchors, exact
#define NBLOCKS BD           // one block per batch row

// Numerically-stable softplus matching jax.nn.softplus
__device__ __forceinline__ float softplus(float x) {
    return fmaxf(x, 0.0f) + log1pf(__expf(-fabsf(x)));
}

__global__ __launch_bounds__(256, 4) void sg_partial(
    const int* __restrict__ walk, const int* __restrict__ neg,
    const float* __restrict__ embed, float* __restrict__ ws)
{
    __shared__ float s_wsum[WAVES_PER_BLOCK];
    const int tid  = threadIdx.x;
    const int lane = tid & 63;
    // force wave id into an SGPR so all index loads scalarize (s_load)
    const int wave = __builtin_amdgcn_readfirstlane(tid >> 6);
    const int b    = blockIdx.x;
    const int a0   = wave * PAIRS_PER_WAVE;

    const float* erow = embed + (size_t)(lane * 2);       // lane's float2 slot
    const int*   wrow = walk + b * LW + a0;               // wave-uniform
    const int*   nrow = neg + (size_t)(b * AA + a0) * NEGS;

    // rolling window of 5 walk-row fragments: r[j] = embed[walk[b][a0+i+j]]
    float2 r[5];
    #pragma unroll
    for (int j = 0; j < 5; ++j)
        r[j] = *(const float2*)(erow + (size_t)wrow[j] * D);

    const bool hi1 = lane & 1;   // selects pos/neg half in stage 1
    const bool hi2 = lane & 2;
    const bool hi3 = lane & 4;

    float wsum = 0.0f;

    #pragma unroll
    for (int i = 0; i < PAIRS_PER_WAVE; ++i) {
        const int4 nv = *(const int4*)(nrow + i * NEGS);  // uniform -> s_load
        const float2 e4 = *(const float2*)(erow + (size_t)nv.x * D);
        const float2 e5 = *(const float2*)(erow + (size_t)nv.y * D);
        const float2 e6 = *(const float2*)(erow + (size_t)nv.z * D);
        const float2 e7 = *(const float2*)(erow + (size_t)nv.w * D);

        const float2 ea = r[0];
        float a0v = fmaf(ea.x, r[1].x, ea.y * r[1].y);
        float a1v = fmaf(ea.x, r[2].x, ea.y * r[2].y);
        float a2v = fmaf(ea.x, r[3].x, ea.y * r[3].y);
        float a3v = fmaf(ea.x, r[4].x, ea.y * r[4].y);
        float a4v = fmaf(ea.x, e4.x,  ea.y * e4.y);
        float a5v = fmaf(ea.x, e5.x,  ea.y * e5.y);
        float a6v = fmaf(ea.x, e6.x,  ea.y * e6.y);
        float a7v = fmaf(ea.x, e7.x,  ea.y * e7.y);

        // reduce-scatter butterfly: 10 shuffles total (vs 48 full-butterfly).
        // After stage 3 each lane holds ONE logit (id in lane bits; bit0=1 => neg).
        float b0 = (hi1 ? a4v : a0v) + __shfl_xor(hi1 ? a0v : a4v, 1);
        float b1 = (hi1 ? a5v : a1v) + __shfl_xor(hi1 ? a1v : a5v, 1);
        float b2 = (hi1 ? a6v : a2v) + __shfl_xor(hi1 ? a2v : a6v, 1);
        float b3 = (hi1 ? a7v : a3v) + __shfl_xor(hi1 ? a3v : a7v, 1);

        float c0 = (hi2 ? b2 : b0) + __shfl_xor(hi2 ? b0 : b2, 2);
        float c1 = (hi2 ? b3 : b1) + __shfl_xor(hi2 ? b1 : b3, 2);

        float dv = (hi3 ? c1 : c0) + __shfl_xor(hi3 ? c0 : c1, 4);
        dv += __shfl_xor(dv, 8);
        dv += __shfl_xor(dv, 16);
        dv += __shfl_xor(dv, 32);
        // dv = fully-reduced logit j(lane&7), replicated 8x across the wave.
        // pos logits need softplus(-x), neg logits softplus(+x); neg iff bit0.
        wsum += softplus(hi1 ? dv : -dv);

        // slide the window: one new walk row per pair
        if (i < PAIRS_PER_WAVE - 1) {
            #pragma unroll
            for (int j = 0; j < 4; ++j) r[j] = r[j + 1];
            r[4] = *(const float2*)(erow + (size_t)wrow[i + 5] * D);
        }
    }

    // lanes hold different logits' softplus sums -> sum across wave, /8 replication
    #pragma unroll
    for (int m = 1; m < 64; m <<= 1) wsum += __shfl_xor(wsum, m);

    if (lane == 0) s_wsum[wave] = wsum * 0.125f;
    __syncthreads();
    if (tid == 0)
        ws[blockIdx.x] = s_wsum[0] + s_wsum[1] + s_wsum[2] + s_wsum[3];
}

__global__ __launch_bounds__(256) void sg_reduce(
    const float* __restrict__ ws, float* __restrict__ out)
{
    __shared__ float s[4];
    const int tid = threadIdx.x;
    float sum = 0.0f;
    #pragma unroll
    for (int i = 0; i < NBLOCKS / 256; ++i) sum += ws[tid + i * 256];
    #pragma unroll
    for (int m = 1; m < 64; m <<= 1) sum += __shfl_xor(sum, m);
    const int wave = tid >> 6;
    const int lane = tid & 63;
    if (lane == 0) s[wave] = sum;
    __syncthreads();
    if (tid == 0) {
        const float total = (float)((size_t)PAIRS * 8);   // 622592 logits
        out[0] = (s[0] + s[1] + s[2] + s[3]) * (1.0f / total);
    }
}

extern "C" void kernel_launch(void* const* d_in, const int* in_sizes, int n_in,
                              void* d_out, int out_size, void* d_ws, size_t ws_size,
                              hipStream_t stream) {
    const int*   walk  = (const int*)d_in[0];
    const int*   neg   = (const int*)d_in[1];
    const float* embed = (const float*)d_in[2];
    float* ws  = (float*)d_ws;   // NBLOCKS floats of scratch (4 KB)
    float* out = (float*)d_out;

    sg_partial<<<NBLOCKS, 256, 0, stream>>>(walk, neg, embed, ws);
    sg_reduce<<<1, 256, 0, stream>>>(ws, out);
}